// Round 10
// baseline (447.833 us; speedup 1.0000x reference)
//
#include <hip/hip_runtime.h>

// Simple_Cross2: x[16384,512] -> cross -> 2048 -> 2048 -> 1024 -> 512 -> 1
// bf16 MFMA (16x16x32) GEMMs, fp32 accumulate, fused bias+relu.
// R2: BK=64 + XOR swizzle -> 0 conflicts. R3: 64x128 wave tile -> G2 121us.
// R4/R5/R8 structural attempts FAILED. R6/R7: head fusion, merged prep -> 345.5.
// R9 FAILED (reverted): convert-in-G1 blocks carried GEMM LDS/VGPR footprint.
// R10: LDS-total-BW analysis: R7 moves 288KB/CU-iter through the 128 B/cyc
//      LDS pipe (= measured 2270 cyc/iter). A-operand moved to direct
//      global->VGPR loads (L1-served, separate pipe), register-double-buffered
//      across the K-iter. LDS traffic -33%, As array gone (LDS 48->32KB),
//      hot barrier drain waits on B only.

#define BK 64

typedef __bf16 bf16x8 __attribute__((ext_vector_type(8)));
typedef float  f32x4  __attribute__((ext_vector_type(4)));
typedef unsigned short u16x4 __attribute__((ext_vector_type(4)));

__device__ __forceinline__ unsigned short f2bf(float f) {
    unsigned int u = __builtin_bit_cast(unsigned int, f);
    u += 0x7fffu + ((u >> 16) & 1u);          // round-to-nearest-even
    return (unsigned short)(u >> 16);
}

__device__ __forceinline__ void async16(const void* g, void* l) {
    __builtin_amdgcn_global_load_lds(
        (const __attribute__((address_space(1))) unsigned int*)g,
        (__attribute__((address_space(3))) unsigned int*)l,
        16, 0, 0);
}

// ---------------------------------------------------------------------------
// C[M,N] = relu(A[M,K] * B[N,K]^T + bias[N]); bf16 in/out, fp32 acc.
// B staged via swizzled LDS (0-conflict, proven); A-fragments loaded DIRECTLY
// global->VGPR (reg double-buffer, issued post-barrier1 -> cold at barrier2).
// bm-fast grid (A L3-resident per bn-group).
// Bs layout: elem(row,c) at row*64 + (((c>>3) ^ (row&7))*8 + (c&7))
// ---------------------------------------------------------------------------
template<int BN>
__global__ __launch_bounds__(256, 2)
void gemm_bt_bias_relu(const unsigned short* __restrict__ A,
                       const unsigned short* __restrict__ B,
                       const float* __restrict__ bias,
                       unsigned short* __restrict__ C,
                       int N, int K)
{
    constexpr int JT = BN / 32;               // B staging issues / acc cols
    __shared__ __align__(16) unsigned short Bs[BN * BK];

    const int tid  = threadIdx.x;
    const int lane = tid & 63;
    const int wave = tid >> 6;
    const int quad = lane >> 4;
    const int l16  = lane & 15;

    const int bm = blockIdx.x * 128;
    const int bn = blockIdx.y * BN;
    const int wm = (wave & 1) * 64;
    const int wn = (wave >> 1) * (BN / 2);

    // B staging map (unchanged, proven conflict-free)
    const int lrow = tid >> 3;
    const int gcol = ((tid & 7) ^ (lrow & 7)) * 8;
    const unsigned short* gbBase = B + (size_t)(bn + lrow) * K + gcol;
    unsigned short* lB = Bs + tid * 8;

    // B fragment read setup
    const int xa = l16 & 7;
    const unsigned short* Bs_w = Bs + (wn + l16) * BK;
    const int c0 = (quad ^ xa) * 8;
    const int c1 = ((quad ^ 4) ^ xa) * 8;

    // A direct per-row pointers: row = bm+wm+i*16+l16, col base = quad*8
    const unsigned short* gA[4];
#pragma unroll
    for (int i = 0; i < 4; ++i)
        gA[i] = A + (size_t)(bm + wm + i * 16 + l16) * K + quad * 8;

    f32x4 acc[4][JT] = {};
    bf16x8 afc[4][2], afn[4][2];

    // preload A fragments for k=0
#pragma unroll
    for (int i = 0; i < 4; ++i)
#pragma unroll
        for (int kk = 0; kk < 2; ++kk)
            afc[i][kk] = *(const bf16x8*)(gA[i] + kk * 32);

    const int nk = K / BK;
    for (int k = 0; k < nk; ++k) {
        const int k0 = k * BK;
#pragma unroll
        for (int i = 0; i < JT; ++i)
            async16(gbBase + (size_t)(i * 32) * K + k0, lB + i * 2048);
        __syncthreads();                      // drains B(k) [hot] + afn [cold]

        if (k + 1 < nk) {                     // issue A(k+1): cold by barrier2
#pragma unroll
            for (int i = 0; i < 4; ++i)
#pragma unroll
                for (int kk = 0; kk < 2; ++kk)
                    afn[i][kk] = *(const bf16x8*)(gA[i] + k0 + BK + kk * 32);
        }

#pragma unroll
        for (int kk = 0; kk < 2; ++kk) {
            const int cs = kk ? c1 : c0;
            bf16x8 bfr[JT];
#pragma unroll
            for (int j = 0; j < JT; ++j) bfr[j] = *(const bf16x8*)(Bs_w + j * 16 * BK + cs);
#pragma unroll
            for (int i = 0; i < 4; ++i)
#pragma unroll
                for (int j = 0; j < JT; ++j)
                    acc[i][j] = __builtin_amdgcn_mfma_f32_16x16x32_bf16(
                        afc[i][kk], bfr[j], acc[i][j], 0, 0, 0);
        }
        __syncthreads();                      // protect Bs overwrite
#pragma unroll
        for (int i = 0; i < 4; ++i)
#pragma unroll
            for (int kk = 0; kk < 2; ++kk)
                afc[i][kk] = afn[i][kk];
    }

    float bv[JT];
#pragma unroll
    for (int j = 0; j < JT; ++j) bv[j] = bias[bn + wn + j * 16 + l16];

#pragma unroll
    for (int i = 0; i < 4; ++i) {
        const int row0 = bm + wm + i * 16 + quad * 4;
#pragma unroll
        for (int j = 0; j < JT; ++j) {
            const int col = bn + wn + j * 16 + l16;
#pragma unroll
            for (int r = 0; r < 4; ++r) {
                float v = acc[i][j][r] + bv[j];
                v = fmaxf(v, 0.0f);
                C[(size_t)(row0 + r) * N + col] = f2bf(v);
            }
        }
    }
}

// ---------------------------------------------------------------------------
// G4 + head fused, same A-direct structure. h4 never stored; partial
// dot(h4_row, Wo_cols) atomicAdd'ed into out[row] (pre-init to bo in prep).
// ---------------------------------------------------------------------------
__global__ __launch_bounds__(256, 2)
void gemm_bt_head(const unsigned short* __restrict__ A,
                  const unsigned short* __restrict__ B,
                  const float* __restrict__ bias,
                  const float* __restrict__ Wo,
                  float* __restrict__ out,
                  int N, int K)
{
    constexpr int BN = 128, JT = 4;
    __shared__ __align__(16) unsigned short Bs[BN * BK];

    const int tid  = threadIdx.x;
    const int lane = tid & 63;
    const int wave = tid >> 6;
    const int quad = lane >> 4;
    const int l16  = lane & 15;

    const int bm = blockIdx.x * 128;
    const int bn = blockIdx.y * BN;
    const int wm = (wave & 1) * 64;
    const int wn = (wave >> 1) * 64;

    const int lrow = tid >> 3;
    const int gcol = ((tid & 7) ^ (lrow & 7)) * 8;
    const unsigned short* gbBase = B + (size_t)(bn + lrow) * K + gcol;
    unsigned short* lB = Bs + tid * 8;

    const int xa = l16 & 7;
    const unsigned short* Bs_w = Bs + (wn + l16) * BK;
    const int c0 = (quad ^ xa) * 8;
    const int c1 = ((quad ^ 4) ^ xa) * 8;

    const unsigned short* gA[4];
#pragma unroll
    for (int i = 0; i < 4; ++i)
        gA[i] = A + (size_t)(bm + wm + i * 16 + l16) * K + quad * 8;

    f32x4 acc[4][JT] = {};
    bf16x8 afc[4][2], afn[4][2];
#pragma unroll
    for (int i = 0; i < 4; ++i)
#pragma unroll
        for (int kk = 0; kk < 2; ++kk)
            afc[i][kk] = *(const bf16x8*)(gA[i] + kk * 32);

    const int nk = K / BK;
    for (int k = 0; k < nk; ++k) {
        const int k0 = k * BK;
#pragma unroll
        for (int i = 0; i < JT; ++i)
            async16(gbBase + (size_t)(i * 32) * K + k0, lB + i * 2048);
        __syncthreads();

        if (k + 1 < nk) {
#pragma unroll
            for (int i = 0; i < 4; ++i)
#pragma unroll
                for (int kk = 0; kk < 2; ++kk)
                    afn[i][kk] = *(const bf16x8*)(gA[i] + k0 + BK + kk * 32);
        }

#pragma unroll
        for (int kk = 0; kk < 2; ++kk) {
            const int cs = kk ? c1 : c0;
            bf16x8 bfr[JT];
#pragma unroll
            for (int j = 0; j < JT; ++j) bfr[j] = *(const bf16x8*)(Bs_w + j * 16 * BK + cs);
#pragma unroll
            for (int i = 0; i < 4; ++i)
#pragma unroll
                for (int j = 0; j < JT; ++j)
                    acc[i][j] = __builtin_amdgcn_mfma_f32_16x16x32_bf16(
                        afc[i][kk], bfr[j], acc[i][j], 0, 0, 0);
        }
        __syncthreads();
#pragma unroll
        for (int i = 0; i < 4; ++i)
#pragma unroll
            for (int kk = 0; kk < 2; ++kk)
                afc[i][kk] = afn[i][kk];
    }

    float bv[JT], wov[JT];
#pragma unroll
    for (int j = 0; j < JT; ++j) {
        const int col = bn + wn + j * 16 + l16;
        bv[j]  = bias[col];
        wov[j] = Wo[col];
    }

#pragma unroll
    for (int i = 0; i < 4; ++i) {
#pragma unroll
        for (int r = 0; r < 4; ++r) {
            float ws = 0.f;
#pragma unroll
            for (int j = 0; j < JT; ++j) {
                float v = acc[i][j][r] + bv[j];
                v = fmaxf(v, 0.0f);
                ws += v * wov[j];
            }
#pragma unroll
            for (int off = 8; off > 0; off >>= 1)
                ws += __shfl_xor(ws, off, 64);
            if (l16 == 0) {
                const int row = bm + wm + i * 16 + quad * 4 + r;
                atomicAdd(&out[row], ws);
            }
        }
    }
}

// ---------------------------------------------------------------------------
// Merged prep (R7): [0,7680) convert W1..W4 fp32->bf16; [7680,11776) cross;
// [11776,11840) init out[m] = bo.
// vec4 segments: W1 262144, W2 1048576, W3 524288, W4 131072 (cum 1966080)
// ---------------------------------------------------------------------------
__global__ __launch_bounds__(256)
void prep_kernel(const float* __restrict__ x, const float* __restrict__ cw,
                 const float* __restrict__ cb, unsigned short* __restrict__ h0,
                 const float* __restrict__ s1, const float* __restrict__ s2,
                 const float* __restrict__ s3, const float* __restrict__ s4,
                 unsigned short* __restrict__ d1, unsigned short* __restrict__ d2,
                 unsigned short* __restrict__ d3, unsigned short* __restrict__ d4,
                 const float* __restrict__ bo, float* __restrict__ out)
{
    const int b = blockIdx.x;
    if (b < 7680) {
        long t = (long)b * 256 + threadIdx.x;
        const float* s; unsigned short* d; long off;
        if (t < 262144L)       { s = s1; d = d1; off = t; }
        else if (t < 1310720L) { s = s2; d = d2; off = t - 262144L; }
        else if (t < 1835008L) { s = s3; d = d3; off = t - 1310720L; }
        else                   { s = s4; d = d4; off = t - 1835008L; }
        f32x4 f = *(const f32x4*)(s + off * 4);
        u16x4 o;
#pragma unroll
        for (int i = 0; i < 4; ++i) o[i] = f2bf(f[i]);
        *(u16x4*)(d + off * 4) = o;
    } else if (b < 11776) {
        const int row  = (b - 7680) * 4 + (threadIdx.x >> 6);
        const int lane = threadIdx.x & 63;
        const float* xr = x + (size_t)row * 512;
        float xv[8];
        float s = 0.f;
#pragma unroll
        for (int i = 0; i < 8; ++i) {
            const int c = lane + i * 64;
            xv[i] = xr[c];
            s += xv[i] * cw[c];
        }
#pragma unroll
        for (int off = 32; off > 0; off >>= 1) s += __shfl_down(s, off, 64);
        s = __shfl(s, 0, 64);
        unsigned short* hr = h0 + (size_t)row * 512;
#pragma unroll
        for (int i = 0; i < 8; ++i) {
            const int c = lane + i * 64;
            hr[c] = f2bf(xv[i] * s + cb[c] + xv[i]);
        }
    } else {
        const int t = (b - 11776) * 256 + threadIdx.x;   // 64 blocks = 16384
        out[t] = bo[0];
    }
}

// ---------------------------------------------------------------------------
extern "C" void kernel_launch(void* const* d_in, const int* in_sizes, int n_in,
                              void* d_out, int out_size, void* d_ws, size_t ws_size,
                              hipStream_t stream)
{
    const float* x  = (const float*)d_in[0];
    const float* cw = (const float*)d_in[1];
    const float* cb = (const float*)d_in[2];
    const float* W1 = (const float*)d_in[3];  const float* b1 = (const float*)d_in[4];
    const float* W2 = (const float*)d_in[5];  const float* b2 = (const float*)d_in[6];
    const float* W3 = (const float*)d_in[7];  const float* b3 = (const float*)d_in[8];
    const float* W4 = (const float*)d_in[9];  const float* b4 = (const float*)d_in[10];
    const float* Wo = (const float*)d_in[11]; const float* bo = (const float*)d_in[12];
    float* out = (float*)d_out;

    // workspace carve (~143 MB)
    char* p = (char*)d_ws;
    unsigned short* wb1 = (unsigned short*)p; p += (size_t)2048 * 512  * 2;
    unsigned short* wb2 = (unsigned short*)p; p += (size_t)2048 * 2048 * 2;
    unsigned short* wb3 = (unsigned short*)p; p += (size_t)1024 * 2048 * 2;
    unsigned short* wb4 = (unsigned short*)p; p += (size_t)512  * 1024 * 2;
    unsigned short* actA = (unsigned short*)p; p += (size_t)16384 * 2048 * 2; // h0,h2
    unsigned short* actB = (unsigned short*)p;                                // h1,h3

    prep_kernel<<<11840, 256, 0, stream>>>(x, cw, cb, actA,
                                           W1, W2, W3, W4, wb1, wb2, wb3, wb4,
                                           bo, out);

    // h1 = relu(h0 @ W1^T + b1)   [16384,2048], K=512
    gemm_bt_bias_relu<256><<<dim3(128, 8), 256, 0, stream>>>(actA, wb1, b1, actB, 2048, 512);
    // h2 = relu(h1 @ W2^T + b2)   [16384,2048], K=2048
    gemm_bt_bias_relu<256><<<dim3(128, 8), 256, 0, stream>>>(actB, wb2, b2, actA, 2048, 2048);
    // h3 = relu(h2 @ W3^T + b3)   [16384,1024], K=2048
    gemm_bt_bias_relu<256><<<dim3(128, 4), 256, 0, stream>>>(actA, wb3, b3, actB, 1024, 2048);
    // out += sum_cols relu(h3 @ W4^T + b4) * Wo   [16384,512] fused head
    gemm_bt_head<<<dim3(128, 4), 256, 0, stream>>>(actB, wb4, b4, Wo, out, 512, 1024);
}

// Round 11
// 362.727 us; speedup vs baseline: 1.2346x; 1.2346x over previous
//
#include <hip/hip_runtime.h>

// Simple_Cross2: x[16384,512] -> cross -> 2048 -> 2048 -> 1024 -> 512 -> 1
// bf16 MFMA (16x16x32) GEMMs, fp32 accumulate, fused bias+relu.
// R2: BK=64 + XOR swizzle -> 0 conflicts. R3: 64x128 wave tile -> G2 121us.
// R4/R5/R8/R10 structural attacks on the K-loop ALL FAILED (barrier-drain /
//   conflict / occupancy / coalescing); G2 inner loop converged at ~121us.
// R6/R7: head fused into G4, merged prep, bm-fast grid -> 345.5us BEST.
// R9 FAILED: convert-in-G1 (resource footprint). R10 FAILED: A-direct (uncoalesced).
// R11: small-GEMM occupancy. G1+G3+G4h run ~650 TF vs G2's 1136 (short K /
//   512-block grids with zero tail slack). BN=128 geometry (R2-proven clean)
//   + __launch_bounds__(256,3) -> 3 blocks/CU, 2x block count for G1/G3.
//   G2 stays the exact R7 BN=256 kernel.

#define BK 64

typedef __bf16 bf16x8 __attribute__((ext_vector_type(8)));
typedef float  f32x4  __attribute__((ext_vector_type(4)));
typedef unsigned short u16x4 __attribute__((ext_vector_type(4)));

__device__ __forceinline__ unsigned short f2bf(float f) {
    unsigned int u = __builtin_bit_cast(unsigned int, f);
    u += 0x7fffu + ((u >> 16) & 1u);          // round-to-nearest-even
    return (unsigned short)(u >> 16);
}

__device__ __forceinline__ void async16(const void* g, void* l) {
    __builtin_amdgcn_global_load_lds(
        (const __attribute__((address_space(1))) unsigned int*)g,
        (__attribute__((address_space(3))) unsigned int*)l,
        16, 0, 0);
}

// ---------------------------------------------------------------------------
// C[M,N] = relu(A[M,K] * B[N,K]^T + bias[N]); bf16 in/out, fp32 acc.
// Proven R3/R7 loop. bm-fast grid (A L3-resident per bn-group).
// LDS layout: elem(row,c) at row*64 + (((c>>3) ^ (row&7))*8 + (c&7))
// MINW: min waves/EU hint -> blocks/CU (BN=128: 3, BN=256: 2).
// ---------------------------------------------------------------------------
template<int BN, int MINW>
__global__ __launch_bounds__(256, MINW)
void gemm_bt_bias_relu(const unsigned short* __restrict__ A,
                       const unsigned short* __restrict__ B,
                       const float* __restrict__ bias,
                       unsigned short* __restrict__ C,
                       int N, int K)
{
    constexpr int JT = BN / 32;               // staging issues / acc cols
    __shared__ __align__(16) unsigned short As[128 * BK];
    __shared__ __align__(16) unsigned short Bs[BN * BK];

    const int tid  = threadIdx.x;
    const int lane = tid & 63;
    const int wave = tid >> 6;
    const int quad = lane >> 4;
    const int l16  = lane & 15;

    const int bm = blockIdx.x * 128;
    const int bn = blockIdx.y * BN;
    const int wm = (wave & 1) * 64;           // wave tile: 64 x (BN/2)
    const int wn = (wave >> 1) * (BN / 2);

    const int lrow = tid >> 3;
    const int gcol = ((tid & 7) ^ (lrow & 7)) * 8;

    const unsigned short* gaBase = A + (size_t)(bm + lrow) * K + gcol;
    const unsigned short* gbBase = B + (size_t)(bn + lrow) * K + gcol;

    unsigned short* lA = As + tid * 8;
    unsigned short* lB = Bs + tid * 8;

    const int xa = l16 & 7;
    const unsigned short* As_w = As + (wm + l16) * BK;
    const unsigned short* Bs_w = Bs + (wn + l16) * BK;
    const int c0 = (quad ^ xa) * 8;
    const int c1 = ((quad ^ 4) ^ xa) * 8;

    f32x4 acc[4][JT] = {};

    for (int k0 = 0; k0 < K; k0 += BK) {
#pragma unroll
        for (int i = 0; i < 4; ++i)
            async16(gaBase + (size_t)(i * 32) * K + k0, lA + i * 2048);
#pragma unroll
        for (int i = 0; i < JT; ++i)
            async16(gbBase + (size_t)(i * 32) * K + k0, lB + i * 2048);
        __syncthreads();

#pragma unroll
        for (int kk = 0; kk < 2; ++kk) {
            const int cs = kk ? c1 : c0;
            bf16x8 af[4], bfr[JT];
#pragma unroll
            for (int i = 0; i < 4; ++i)  af[i]  = *(const bf16x8*)(As_w + i * 16 * BK + cs);
#pragma unroll
            for (int j = 0; j < JT; ++j) bfr[j] = *(const bf16x8*)(Bs_w + j * 16 * BK + cs);
#pragma unroll
            for (int i = 0; i < 4; ++i)
#pragma unroll
                for (int j = 0; j < JT; ++j)
                    acc[i][j] = __builtin_amdgcn_mfma_f32_16x16x32_bf16(
                        af[i], bfr[j], acc[i][j], 0, 0, 0);
        }
        __syncthreads();
    }

    float bv[JT];
#pragma unroll
    for (int j = 0; j < JT; ++j) bv[j] = bias[bn + wn + j * 16 + l16];

#pragma unroll
    for (int i = 0; i < 4; ++i) {
        const int row0 = bm + wm + i * 16 + quad * 4;
#pragma unroll
        for (int j = 0; j < JT; ++j) {
            const int col = bn + wn + j * 16 + l16;
#pragma unroll
            for (int r = 0; r < 4; ++r) {
                float v = acc[i][j][r] + bv[j];
                v = fmaxf(v, 0.0f);
                C[(size_t)(row0 + r) * N + col] = f2bf(v);
            }
        }
    }
}

// ---------------------------------------------------------------------------
// G4 + head fused (R7): h4 = relu(A @ W4^T + b4) never stored; partial
// dot(h4_row, Wo_cols) atomicAdd'ed into out[row] (pre-init to bo in prep).
// BN=128, min-waves 3 (32KB LDS, small acc -> 3 blocks/CU).
// ---------------------------------------------------------------------------
__global__ __launch_bounds__(256, 3)
void gemm_bt_head(const unsigned short* __restrict__ A,
                  const unsigned short* __restrict__ B,
                  const float* __restrict__ bias,
                  const float* __restrict__ Wo,
                  float* __restrict__ out,
                  int N, int K)
{
    constexpr int BN = 128, JT = 4;
    __shared__ __align__(16) unsigned short As[128 * BK];
    __shared__ __align__(16) unsigned short Bs[BN * BK];

    const int tid  = threadIdx.x;
    const int lane = tid & 63;
    const int wave = tid >> 6;
    const int quad = lane >> 4;
    const int l16  = lane & 15;

    const int bm = blockIdx.x * 128;
    const int bn = blockIdx.y * BN;
    const int wm = (wave & 1) * 64;
    const int wn = (wave >> 1) * 64;

    const int lrow = tid >> 3;
    const int gcol = ((tid & 7) ^ (lrow & 7)) * 8;

    const unsigned short* gaBase = A + (size_t)(bm + lrow) * K + gcol;
    const unsigned short* gbBase = B + (size_t)(bn + lrow) * K + gcol;

    unsigned short* lA = As + tid * 8;
    unsigned short* lB = Bs + tid * 8;

    const int xa = l16 & 7;
    const unsigned short* As_w = As + (wm + l16) * BK;
    const unsigned short* Bs_w = Bs + (wn + l16) * BK;
    const int c0 = (quad ^ xa) * 8;
    const int c1 = ((quad ^ 4) ^ xa) * 8;

    f32x4 acc[4][JT] = {};

    for (int k0 = 0; k0 < K; k0 += BK) {
#pragma unroll
        for (int i = 0; i < 4; ++i)
            async16(gaBase + (size_t)(i * 32) * K + k0, lA + i * 2048);
#pragma unroll
        for (int i = 0; i < JT; ++i)
            async16(gbBase + (size_t)(i * 32) * K + k0, lB + i * 2048);
        __syncthreads();

#pragma unroll
        for (int kk = 0; kk < 2; ++kk) {
            const int cs = kk ? c1 : c0;
            bf16x8 af[4], bfr[JT];
#pragma unroll
            for (int i = 0; i < 4; ++i)  af[i]  = *(const bf16x8*)(As_w + i * 16 * BK + cs);
#pragma unroll
            for (int j = 0; j < JT; ++j) bfr[j] = *(const bf16x8*)(Bs_w + j * 16 * BK + cs);
#pragma unroll
            for (int i = 0; i < 4; ++i)
#pragma unroll
                for (int j = 0; j < JT; ++j)
                    acc[i][j] = __builtin_amdgcn_mfma_f32_16x16x32_bf16(
                        af[i], bfr[j], acc[i][j], 0, 0, 0);
        }
        __syncthreads();
    }

    float bv[JT], wov[JT];
#pragma unroll
    for (int j = 0; j < JT; ++j) {
        const int col = bn + wn + j * 16 + l16;
        bv[j]  = bias[col];
        wov[j] = Wo[col];
    }

#pragma unroll
    for (int i = 0; i < 4; ++i) {
#pragma unroll
        for (int r = 0; r < 4; ++r) {
            float ws = 0.f;
#pragma unroll
            for (int j = 0; j < JT; ++j) {
                float v = acc[i][j][r] + bv[j];
                v = fmaxf(v, 0.0f);
                ws += v * wov[j];
            }
#pragma unroll
            for (int off = 8; off > 0; off >>= 1)
                ws += __shfl_xor(ws, off, 64);
            if (l16 == 0) {
                const int row = bm + wm + i * 16 + quad * 4 + r;
                atomicAdd(&out[row], ws);
            }
        }
    }
}

// ---------------------------------------------------------------------------
// Merged prep (R7): [0,7680) convert W1..W4 fp32->bf16; [7680,11776) cross;
// [11776,11840) init out[m] = bo.
// vec4 segments: W1 262144, W2 1048576, W3 524288, W4 131072 (cum 1966080)
// ---------------------------------------------------------------------------
__global__ __launch_bounds__(256)
void prep_kernel(const float* __restrict__ x, const float* __restrict__ cw,
                 const float* __restrict__ cb, unsigned short* __restrict__ h0,
                 const float* __restrict__ s1, const float* __restrict__ s2,
                 const float* __restrict__ s3, const float* __restrict__ s4,
                 unsigned short* __restrict__ d1, unsigned short* __restrict__ d2,
                 unsigned short* __restrict__ d3, unsigned short* __restrict__ d4,
                 const float* __restrict__ bo, float* __restrict__ out)
{
    const int b = blockIdx.x;
    if (b < 7680) {
        long t = (long)b * 256 + threadIdx.x;
        const float* s; unsigned short* d; long off;
        if (t < 262144L)       { s = s1; d = d1; off = t; }
        else if (t < 1310720L) { s = s2; d = d2; off = t - 262144L; }
        else if (t < 1835008L) { s = s3; d = d3; off = t - 1310720L; }
        else                   { s = s4; d = d4; off = t - 1835008L; }
        f32x4 f = *(const f32x4*)(s + off * 4);
        u16x4 o;
#pragma unroll
        for (int i = 0; i < 4; ++i) o[i] = f2bf(f[i]);
        *(u16x4*)(d + off * 4) = o;
    } else if (b < 11776) {
        const int row  = (b - 7680) * 4 + (threadIdx.x >> 6);
        const int lane = threadIdx.x & 63;
        const float* xr = x + (size_t)row * 512;
        float xv[8];
        float s = 0.f;
#pragma unroll
        for (int i = 0; i < 8; ++i) {
            const int c = lane + i * 64;
            xv[i] = xr[c];
            s += xv[i] * cw[c];
        }
#pragma unroll
        for (int off = 32; off > 0; off >>= 1) s += __shfl_down(s, off, 64);
        s = __shfl(s, 0, 64);
        unsigned short* hr = h0 + (size_t)row * 512;
#pragma unroll
        for (int i = 0; i < 8; ++i) {
            const int c = lane + i * 64;
            hr[c] = f2bf(xv[i] * s + cb[c] + xv[i]);
        }
    } else {
        const int t = (b - 11776) * 256 + threadIdx.x;   // 64 blocks = 16384
        out[t] = bo[0];
    }
}

// ---------------------------------------------------------------------------
extern "C" void kernel_launch(void* const* d_in, const int* in_sizes, int n_in,
                              void* d_out, int out_size, void* d_ws, size_t ws_size,
                              hipStream_t stream)
{
    const float* x  = (const float*)d_in[0];
    const float* cw = (const float*)d_in[1];
    const float* cb = (const float*)d_in[2];
    const float* W1 = (const float*)d_in[3];  const float* b1 = (const float*)d_in[4];
    const float* W2 = (const float*)d_in[5];  const float* b2 = (const float*)d_in[6];
    const float* W3 = (const float*)d_in[7];  const float* b3 = (const float*)d_in[8];
    const float* W4 = (const float*)d_in[9];  const float* b4 = (const float*)d_in[10];
    const float* Wo = (const float*)d_in[11]; const float* bo = (const float*)d_in[12];
    float* out = (float*)d_out;

    // workspace carve (~143 MB)
    char* p = (char*)d_ws;
    unsigned short* wb1 = (unsigned short*)p; p += (size_t)2048 * 512  * 2;
    unsigned short* wb2 = (unsigned short*)p; p += (size_t)2048 * 2048 * 2;
    unsigned short* wb3 = (unsigned short*)p; p += (size_t)1024 * 2048 * 2;
    unsigned short* wb4 = (unsigned short*)p; p += (size_t)512  * 1024 * 2;
    unsigned short* actA = (unsigned short*)p; p += (size_t)16384 * 2048 * 2; // h0,h2
    unsigned short* actB = (unsigned short*)p;                                // h1,h3

    prep_kernel<<<11840, 256, 0, stream>>>(x, cw, cb, actA,
                                           W1, W2, W3, W4, wb1, wb2, wb3, wb4,
                                           bo, out);

    // h1 = relu(h0 @ W1^T + b1)   [16384,2048], K=512  (BN=128, 3 blk/CU)
    gemm_bt_bias_relu<128, 3><<<dim3(128, 16), 256, 0, stream>>>(actA, wb1, b1, actB, 2048, 512);
    // h2 = relu(h1 @ W2^T + b2)   [16384,2048], K=2048 (BN=256, proven best)
    gemm_bt_bias_relu<256, 2><<<dim3(128, 8), 256, 0, stream>>>(actB, wb2, b2, actA, 2048, 2048);
    // h3 = relu(h2 @ W3^T + b3)   [16384,1024], K=2048 (BN=128, 3 blk/CU)
    gemm_bt_bias_relu<128, 3><<<dim3(128, 8), 256, 0, stream>>>(actA, wb3, b3, actB, 1024, 2048);
    // out += sum_cols relu(h3 @ W4^T + b4) * Wo   [16384,512] fused head
    gemm_bt_head<<<dim3(128, 4), 256, 0, stream>>>(actB, wb4, b4, Wo, out, 512, 1024);
}

// Round 12
// 349.702 us; speedup vs baseline: 1.2806x; 1.0372x over previous
//
#include <hip/hip_runtime.h>

// Simple_Cross2: x[16384,512] -> cross -> 2048 -> 2048 -> 1024 -> 512 -> 1
// bf16 MFMA (16x16x32) GEMMs, fp32 accumulate, fused bias+relu.
// FINAL (R12 = R7 verbatim, best-known 345.5us):
//   R2: BK=64 + XOR-swizzled LDS -> 0 bank conflicts.
//   R3: 64x128 wave tile, 128x256 block, bm-fast grid (A L3-resident).
//   R6/R7: N=1 head fused into G4 epilogue (atomicAdd), merged prep.
// Rejected by experiment (kept for the record):
//   R4 same-wave dbuf (vmcnt(0)-at-barrier drains own prefetch), R5 32x32x16
//   (swizzle aliases -> conflicts), R8 producer/consumer waves (1 blk/CU
//   occupancy loss), R9 convert-in-G1 (resource footprint), R10 A-direct
//   (uncoalesced frag loads), R11 BN=128+minw3 retune (net regression).
// G2 = 1136 TF ~ 48% of bf16 µbench ceiling -- the documented HIP-source
// plateau for the 2-barrier K-loop structure (cf. m97/m131-141 notes).

#define BK 64

typedef __bf16 bf16x8 __attribute__((ext_vector_type(8)));
typedef float  f32x4  __attribute__((ext_vector_type(4)));
typedef unsigned short u16x4 __attribute__((ext_vector_type(4)));

__device__ __forceinline__ unsigned short f2bf(float f) {
    unsigned int u = __builtin_bit_cast(unsigned int, f);
    u += 0x7fffu + ((u >> 16) & 1u);          // round-to-nearest-even
    return (unsigned short)(u >> 16);
}

__device__ __forceinline__ void async16(const void* g, void* l) {
    __builtin_amdgcn_global_load_lds(
        (const __attribute__((address_space(1))) unsigned int*)g,
        (__attribute__((address_space(3))) unsigned int*)l,
        16, 0, 0);
}

// ---------------------------------------------------------------------------
// C[M,N] = relu(A[M,K] * B[N,K]^T + bias[N]); bf16 in/out, fp32 acc.
// bm = blockIdx.x (fast) keeps A L3-resident per bn-group.
// LDS layout: elem(row,c) at row*64 + (((c>>3) ^ (row&7))*8 + (c&7))
// ---------------------------------------------------------------------------
template<int BN>
__global__ __launch_bounds__(256, 2)
void gemm_bt_bias_relu(const unsigned short* __restrict__ A,
                       const unsigned short* __restrict__ B,
                       const float* __restrict__ bias,
                       unsigned short* __restrict__ C,
                       int N, int K)
{
    constexpr int JT = BN / 32;               // staging issues / acc cols
    __shared__ __align__(16) unsigned short As[128 * BK];
    __shared__ __align__(16) unsigned short Bs[BN * BK];

    const int tid  = threadIdx.x;
    const int lane = tid & 63;
    const int wave = tid >> 6;
    const int quad = lane >> 4;
    const int l16  = lane & 15;

    const int bm = blockIdx.x * 128;
    const int bn = blockIdx.y * BN;
    const int wm = (wave & 1) * 64;           // wave tile: 64 x (BN/2)
    const int wn = (wave >> 1) * (BN / 2);

    const int lrow = tid >> 3;
    const int gcol = ((tid & 7) ^ (lrow & 7)) * 8;

    const unsigned short* gaBase = A + (size_t)(bm + lrow) * K + gcol;
    const unsigned short* gbBase = B + (size_t)(bn + lrow) * K + gcol;

    unsigned short* lA = As + tid * 8;
    unsigned short* lB = Bs + tid * 8;

    const int xa = l16 & 7;
    const unsigned short* As_w = As + (wm + l16) * BK;
    const unsigned short* Bs_w = Bs + (wn + l16) * BK;
    const int c0 = (quad ^ xa) * 8;
    const int c1 = ((quad ^ 4) ^ xa) * 8;

    f32x4 acc[4][JT] = {};

    for (int k0 = 0; k0 < K; k0 += BK) {
#pragma unroll
        for (int i = 0; i < 4; ++i)
            async16(gaBase + (size_t)(i * 32) * K + k0, lA + i * 2048);
#pragma unroll
        for (int i = 0; i < JT; ++i)
            async16(gbBase + (size_t)(i * 32) * K + k0, lB + i * 2048);
        __syncthreads();

#pragma unroll
        for (int kk = 0; kk < 2; ++kk) {
            const int cs = kk ? c1 : c0;
            bf16x8 af[4], bfr[JT];
#pragma unroll
            for (int i = 0; i < 4; ++i)  af[i]  = *(const bf16x8*)(As_w + i * 16 * BK + cs);
#pragma unroll
            for (int j = 0; j < JT; ++j) bfr[j] = *(const bf16x8*)(Bs_w + j * 16 * BK + cs);
#pragma unroll
            for (int i = 0; i < 4; ++i)
#pragma unroll
                for (int j = 0; j < JT; ++j)
                    acc[i][j] = __builtin_amdgcn_mfma_f32_16x16x32_bf16(
                        af[i], bfr[j], acc[i][j], 0, 0, 0);
        }
        __syncthreads();
    }

    float bv[JT];
#pragma unroll
    for (int j = 0; j < JT; ++j) bv[j] = bias[bn + wn + j * 16 + l16];

#pragma unroll
    for (int i = 0; i < 4; ++i) {
        const int row0 = bm + wm + i * 16 + quad * 4;
#pragma unroll
        for (int j = 0; j < JT; ++j) {
            const int col = bn + wn + j * 16 + l16;
#pragma unroll
            for (int r = 0; r < 4; ++r) {
                float v = acc[i][j][r] + bv[j];
                v = fmaxf(v, 0.0f);
                C[(size_t)(row0 + r) * N + col] = f2bf(v);
            }
        }
    }
}

// ---------------------------------------------------------------------------
// G4 + head fused: h4 = relu(A @ W4^T + b4) never stored; each block
// computes partial dot(h4_row, Wo_cols) and atomicAdds into out[row].
// out pre-initialized to bo in prep_kernel. Block tile 128x128, acc[4][4].
// ---------------------------------------------------------------------------
__global__ __launch_bounds__(256, 2)
void gemm_bt_head(const unsigned short* __restrict__ A,
                  const unsigned short* __restrict__ B,
                  const float* __restrict__ bias,
                  const float* __restrict__ Wo,
                  float* __restrict__ out,
                  int N, int K)
{
    constexpr int BN = 128, JT = 4;
    __shared__ __align__(16) unsigned short As[128 * BK];
    __shared__ __align__(16) unsigned short Bs[BN * BK];

    const int tid  = threadIdx.x;
    const int lane = tid & 63;
    const int wave = tid >> 6;
    const int quad = lane >> 4;
    const int l16  = lane & 15;

    const int bm = blockIdx.x * 128;
    const int bn = blockIdx.y * BN;
    const int wm = (wave & 1) * 64;
    const int wn = (wave >> 1) * 64;

    const int lrow = tid >> 3;
    const int gcol = ((tid & 7) ^ (lrow & 7)) * 8;

    const unsigned short* gaBase = A + (size_t)(bm + lrow) * K + gcol;
    const unsigned short* gbBase = B + (size_t)(bn + lrow) * K + gcol;

    unsigned short* lA = As + tid * 8;
    unsigned short* lB = Bs + tid * 8;

    const int xa = l16 & 7;
    const unsigned short* As_w = As + (wm + l16) * BK;
    const unsigned short* Bs_w = Bs + (wn + l16) * BK;
    const int c0 = (quad ^ xa) * 8;
    const int c1 = ((quad ^ 4) ^ xa) * 8;

    f32x4 acc[4][JT] = {};

    for (int k0 = 0; k0 < K; k0 += BK) {
#pragma unroll
        for (int i = 0; i < 4; ++i)
            async16(gaBase + (size_t)(i * 32) * K + k0, lA + i * 2048);
#pragma unroll
        for (int i = 0; i < JT; ++i)
            async16(gbBase + (size_t)(i * 32) * K + k0, lB + i * 2048);
        __syncthreads();

#pragma unroll
        for (int kk = 0; kk < 2; ++kk) {
            const int cs = kk ? c1 : c0;
            bf16x8 af[4], bfr[JT];
#pragma unroll
            for (int i = 0; i < 4; ++i)  af[i]  = *(const bf16x8*)(As_w + i * 16 * BK + cs);
#pragma unroll
            for (int j = 0; j < JT; ++j) bfr[j] = *(const bf16x8*)(Bs_w + j * 16 * BK + cs);
#pragma unroll
            for (int i = 0; i < 4; ++i)
#pragma unroll
                for (int j = 0; j < JT; ++j)
                    acc[i][j] = __builtin_amdgcn_mfma_f32_16x16x32_bf16(
                        af[i], bfr[j], acc[i][j], 0, 0, 0);
        }
        __syncthreads();
    }

    float bv[JT], wov[JT];
#pragma unroll
    for (int j = 0; j < JT; ++j) {
        const int col = bn + wn + j * 16 + l16;
        bv[j]  = bias[col];
        wov[j] = Wo[col];
    }

#pragma unroll
    for (int i = 0; i < 4; ++i) {
#pragma unroll
        for (int r = 0; r < 4; ++r) {
            float ws = 0.f;
#pragma unroll
            for (int j = 0; j < JT; ++j) {
                float v = acc[i][j][r] + bv[j];
                v = fmaxf(v, 0.0f);
                ws += v * wov[j];
            }
#pragma unroll
            for (int off = 8; off > 0; off >>= 1)
                ws += __shfl_xor(ws, off, 64);
            if (l16 == 0) {
                const int row = bm + wm + i * 16 + quad * 4 + r;
                atomicAdd(&out[row], ws);
            }
        }
    }
}

// ---------------------------------------------------------------------------
// Merged prep: [0,7680) convert W1..W4 fp32->bf16; [7680,11776) cross layer;
// [11776,11840) init out[m] = bo.
// vec4 segments: W1 262144, W2 1048576, W3 524288, W4 131072 (cum 1966080)
// ---------------------------------------------------------------------------
__global__ __launch_bounds__(256)
void prep_kernel(const float* __restrict__ x, const float* __restrict__ cw,
                 const float* __restrict__ cb, unsigned short* __restrict__ h0,
                 const float* __restrict__ s1, const float* __restrict__ s2,
                 const float* __restrict__ s3, const float* __restrict__ s4,
                 unsigned short* __restrict__ d1, unsigned short* __restrict__ d2,
                 unsigned short* __restrict__ d3, unsigned short* __restrict__ d4,
                 const float* __restrict__ bo, float* __restrict__ out)
{
    const int b = blockIdx.x;
    if (b < 7680) {
        long t = (long)b * 256 + threadIdx.x;
        const float* s; unsigned short* d; long off;
        if (t < 262144L)       { s = s1; d = d1; off = t; }
        else if (t < 1310720L) { s = s2; d = d2; off = t - 262144L; }
        else if (t < 1835008L) { s = s3; d = d3; off = t - 1310720L; }
        else                   { s = s4; d = d4; off = t - 1835008L; }
        f32x4 f = *(const f32x4*)(s + off * 4);
        u16x4 o;
#pragma unroll
        for (int i = 0; i < 4; ++i) o[i] = f2bf(f[i]);
        *(u16x4*)(d + off * 4) = o;
    } else if (b < 11776) {
        const int row  = (b - 7680) * 4 + (threadIdx.x >> 6);
        const int lane = threadIdx.x & 63;
        const float* xr = x + (size_t)row * 512;
        float xv[8];
        float s = 0.f;
#pragma unroll
        for (int i = 0; i < 8; ++i) {
            const int c = lane + i * 64;
            xv[i] = xr[c];
            s += xv[i] * cw[c];
        }
#pragma unroll
        for (int off = 32; off > 0; off >>= 1) s += __shfl_down(s, off, 64);
        s = __shfl(s, 0, 64);
        unsigned short* hr = h0 + (size_t)row * 512;
#pragma unroll
        for (int i = 0; i < 8; ++i) {
            const int c = lane + i * 64;
            hr[c] = f2bf(xv[i] * s + cb[c] + xv[i]);
        }
    } else {
        const int t = (b - 11776) * 256 + threadIdx.x;   // 64 blocks = 16384
        out[t] = bo[0];
    }
}

// ---------------------------------------------------------------------------
extern "C" void kernel_launch(void* const* d_in, const int* in_sizes, int n_in,
                              void* d_out, int out_size, void* d_ws, size_t ws_size,
                              hipStream_t stream)
{
    const float* x  = (const float*)d_in[0];
    const float* cw = (const float*)d_in[1];
    const float* cb = (const float*)d_in[2];
    const float* W1 = (const float*)d_in[3];  const float* b1 = (const float*)d_in[4];
    const float* W2 = (const float*)d_in[5];  const float* b2 = (const float*)d_in[6];
    const float* W3 = (const float*)d_in[7];  const float* b3 = (const float*)d_in[8];
    const float* W4 = (const float*)d_in[9];  const float* b4 = (const float*)d_in[10];
    const float* Wo = (const float*)d_in[11]; const float* bo = (const float*)d_in[12];
    float* out = (float*)d_out;

    // workspace carve (~143 MB)
    char* p = (char*)d_ws;
    unsigned short* wb1 = (unsigned short*)p; p += (size_t)2048 * 512  * 2;
    unsigned short* wb2 = (unsigned short*)p; p += (size_t)2048 * 2048 * 2;
    unsigned short* wb3 = (unsigned short*)p; p += (size_t)1024 * 2048 * 2;
    unsigned short* wb4 = (unsigned short*)p; p += (size_t)512  * 1024 * 2;
    unsigned short* actA = (unsigned short*)p; p += (size_t)16384 * 2048 * 2; // h0,h2
    unsigned short* actB = (unsigned short*)p;                                // h1,h3

    prep_kernel<<<11840, 256, 0, stream>>>(x, cw, cb, actA,
                                           W1, W2, W3, W4, wb1, wb2, wb3, wb4,
                                           bo, out);

    // h1 = relu(h0 @ W1^T + b1)   [16384,2048], K=512
    gemm_bt_bias_relu<256><<<dim3(128, 8), 256, 0, stream>>>(actA, wb1, b1, actB, 2048, 512);
    // h2 = relu(h1 @ W2^T + b2)   [16384,2048], K=2048
    gemm_bt_bias_relu<256><<<dim3(128, 8), 256, 0, stream>>>(actB, wb2, b2, actA, 2048, 2048);
    // h3 = relu(h2 @ W3^T + b3)   [16384,1024], K=2048
    gemm_bt_bias_relu<256><<<dim3(128, 4), 256, 0, stream>>>(actA, wb3, b3, actB, 1024, 2048);
    // out += sum_cols relu(h3 @ W4^T + b4) * Wo   [16384,512] fused head
    gemm_bt_head<<<dim3(128, 4), 256, 0, stream>>>(actB, wb4, b4, Wo, out, 512, 1024);
}